// Round 6
// baseline (881.736 us; speedup 1.0000x reference)
//
#include <hip/hip_runtime.h>
#include <hip/hip_cooperative_groups.h>

namespace cg = cooperative_groups;

#define F 32  // F_IN == F_OUT == 32

typedef __attribute__((ext_vector_type(4))) unsigned short us4;
typedef __attribute__((ext_vector_type(4))) float f4;
typedef __attribute__((ext_vector_type(8))) __bf16 bf8;

// ---- bf16 helpers (manual RNE) ----
static __device__ __forceinline__ unsigned short f2bf(float f) {
    unsigned int u = __float_as_uint(f);
    u += 0x7FFF + ((u >> 16) & 1);
    return (unsigned short)(u >> 16);
}
static __device__ __forceinline__ float bf2f(unsigned short s) {
    return __uint_as_float(((unsigned int)s) << 16);
}

// Fused prologue. Blocks [0, nxw): y = x @ W^T via MFMA, 64 nodes/block
// (16-node tile per wave, no LDS). hi/lo bf16 split of x and W keeps
// precision at the fp32-FMA level (store-rounding dominates).
// Blocks [nxw, ...): CSR row-ptr boundary scatter from sorted rows.
__global__ __launch_bounds__(256) void prologue_kernel(
    const float* __restrict__ x, const float* __restrict__ W,
    const int* __restrict__ rows,
    unsigned short* __restrict__ y, int* __restrict__ ptr,
    int N, int E, int nxw) {
    int b = blockIdx.x;
    int t = threadIdx.x;
    if (b < nxw) {
        int lane = t & 63;
        int n0 = (b * 4 + (t >> 6)) * 16;     // 16-node tile per wave
        if (n0 >= N) return;
        int m  = lane & 15;
        int kb = lane >> 4;                    // 0..3 -> k-block of 8
        int k0 = kb * 8;

        int ra = n0 + m; if (ra > N - 1) ra = N - 1;
        const f4* __restrict__ xr = (const f4*)(x + (size_t)ra * F + k0);
        f4 xa = xr[0], xb = xr[1];
        float fx[8] = {xa.x, xa.y, xa.z, xa.w, xb.x, xb.y, xb.z, xb.w};
        bf8 Ah, Al;
        #pragma unroll
        for (int i = 0; i < 8; ++i) {
            __bf16 h = (__bf16)fx[i];
            Ah[i] = h;
            Al[i] = (__bf16)(fx[i] - (float)h);
        }

        const f4* __restrict__ w0 = (const f4*)(W + (size_t)m * F + k0);
        const f4* __restrict__ w1 = (const f4*)(W + (size_t)(m + 16) * F + k0);
        f4 wa = w0[0], wb = w0[1], wc = w1[0], wd = w1[1];
        float fw0[8] = {wa.x, wa.y, wa.z, wa.w, wb.x, wb.y, wb.z, wb.w};
        float fw1[8] = {wc.x, wc.y, wc.z, wc.w, wd.x, wd.y, wd.z, wd.w};
        bf8 B0h, B0l, B1h, B1l;
        #pragma unroll
        for (int i = 0; i < 8; ++i) {
            __bf16 h0 = (__bf16)fw0[i];
            B0h[i] = h0;
            B0l[i] = (__bf16)(fw0[i] - (float)h0);
            __bf16 h1 = (__bf16)fw1[i];
            B1h[i] = h1;
            B1l[i] = (__bf16)(fw1[i] - (float)h1);
        }

        f4 acc0 = {0.f, 0.f, 0.f, 0.f}, acc1 = {0.f, 0.f, 0.f, 0.f};
        acc0 = __builtin_amdgcn_mfma_f32_16x16x32_bf16(Ah, B0h, acc0, 0, 0, 0);
        acc0 = __builtin_amdgcn_mfma_f32_16x16x32_bf16(Ah, B0l, acc0, 0, 0, 0);
        acc0 = __builtin_amdgcn_mfma_f32_16x16x32_bf16(Al, B0h, acc0, 0, 0, 0);
        acc1 = __builtin_amdgcn_mfma_f32_16x16x32_bf16(Ah, B1h, acc1, 0, 0, 0);
        acc1 = __builtin_amdgcn_mfma_f32_16x16x32_bf16(Ah, B1l, acc1, 0, 0, 0);
        acc1 = __builtin_amdgcn_mfma_f32_16x16x32_bf16(Al, B1h, acc1, 0, 0, 0);

        // C/D layout (verified m89): col = lane&15, row = (lane>>4)*4 + r
        int mr = n0 + kb * 4;
        #pragma unroll
        for (int r = 0; r < 4; ++r) {
            int row = mr + r;
            if (row < N) {
                y[(size_t)row * F + m]      = f2bf(acc0[r]);
                y[(size_t)row * F + m + 16] = f2bf(acc1[r]);
            }
        }
    } else {
        int e = (b - nxw) * 256 + t;
        if (e > E) return;
        int prev = (e == 0) ? -1 : rows[e - 1];
        int cur  = (e == E) ? N  : rows[e];
        for (int r = prev + 1; r <= cur; ++r) ptr[r] = e;
    }
}

// Cooperative persistent gather kernel with column-half phasing.
// All blocks resident; per node-tile, phase 0 gathers only cols < H and
// phase 1 cols >= H, with grid.sync() at phase boundaries so every
// resident block hits the same 3.2 MB half of y -> per-XCD-L2-resident.
// Accumulators live in registers across phases. Wave = 8 nodes x 8 lanes;
// 8-edge unroll with index prefetch (R1 shape). Masked-off gathers are
// exec-masked (no line request); r zero-init avoids NaN*0.
__global__ __launch_bounds__(256) void gnn_coop_kernel(
    const unsigned short* __restrict__ y,
    const int*   __restrict__ cols,
    const float* __restrict__ vals,
    const int*   __restrict__ row_ptr,
    const float* __restrict__ bias,
    float*       __restrict__ out, int N, int H, int T) {
    cg::grid_group grid = cg::this_grid();
    int t = threadIdx.x;
    int lane = t & 63;
    int g = lane >> 3;           // node group 0..7
    int l = lane & 7;            // feature slice 4l..4l+3
    const us4* __restrict__ y4 = (const us4*)y;   // 8 x us4 per row

    for (int tile = 0; tile < T; ++tile) {
        int n = ((tile * gridDim.x + blockIdx.x) * 4 + (t >> 6)) * 8 + g;
        int start = 0, end = 0;
        if (n < N) { start = row_ptr[n]; end = row_ptr[n + 1]; }
        int lim = end - 1; if (lim < 0) lim = 0;

        float a0[4] = {0.f, 0.f, 0.f, 0.f};
        float a1[4] = {0.f, 0.f, 0.f, 0.f};

        for (int h = 0; h < 2; ++h) {
            // prefetch first index chunk (edge slice is L1-hot in phase 1)
            int cc[8]; float vv[8];
            #pragma unroll
            for (int k = 0; k < 8; ++k) {
                int ek = start + k;
                int ec = (ek < end) ? ek : lim;
                cc[k] = cols[ec];
                vv[k] = vals[ec];
            }
            for (int e = start; e < end; e += 8) {
                int c[8]; float v[8];
                #pragma unroll
                for (int k = 0; k < 8; ++k) {
                    c[k] = cc[k];
                    v[k] = (e + k < end) ? vv[k] : 0.0f;
                }
                #pragma unroll
                for (int k = 0; k < 8; ++k) {
                    int ek = e + 8 + k;
                    int ec = (ek < end) ? ek : lim;
                    cc[k] = cols[ec];
                    vv[k] = vals[ec];
                }
                us4 r[8];
                #pragma unroll
                for (int k = 0; k < 8; ++k) {
                    us4 z = {0, 0, 0, 0};
                    r[k] = z;
                    bool inh = h ? (c[k] >= H) : (c[k] < H);
                    bool act = inh & (e + k < end);
                    if (act) r[k] = y4[(size_t)c[k] * 8 + l];
                }
                #pragma unroll
                for (int k = 0; k < 8; ++k) {
                    float* a = (k & 1) ? a1 : a0;  // 2 accumulator chains
                    #pragma unroll
                    for (int i = 0; i < 4; ++i)
                        a[i] = fmaf(bf2f(r[k][i]), v[k], a[i]);
                }
            }
            if (h == 0) grid.sync();   // phase boundary: switch y half
        }

        if (n < N) {
            const f4* __restrict__ b4 = (const f4*)bias;
            f4 bb = b4[l];
            f4 o;
            o.x = fmaxf(a0[0] + a1[0] + bb.x, 0.f);
            o.y = fmaxf(a0[1] + a1[1] + bb.y, 0.f);
            o.z = fmaxf(a0[2] + a1[2] + bb.z, 0.f);
            o.w = fmaxf(a0[3] + a1[3] + bb.w, 0.f);
            f4* op = (f4*)(out + (size_t)n * F + l * 4);
            __builtin_nontemporal_store(o, op);
        }
        if (tile + 1 < T) grid.sync(); // tile boundary
    }
}

// Plain (non-cooperative) R1-shape kernel: fallback if coop launch fails.
__global__ __launch_bounds__(256) void gnn_kernel(
    const unsigned short* __restrict__ y,
    const int*   __restrict__ cols,
    const float* __restrict__ vals,
    const int*   __restrict__ row_ptr,
    const float* __restrict__ bias,
    float*       __restrict__ out, int N) {
    int t = threadIdx.x;
    int lane = t & 63;
    int g = lane >> 3;
    int l = lane & 7;
    int n = (blockIdx.x * 4 + (t >> 6)) * 8 + g;
    int start = 0, end = 0;
    if (n < N) { start = row_ptr[n]; end = row_ptr[n + 1]; }
    const us4* __restrict__ y4 = (const us4*)y;
    float a0[4], a1[4];
    #pragma unroll
    for (int i = 0; i < 4; ++i) { a0[i] = 0.f; a1[i] = 0.f; }
    int lim = end - 1; if (lim < 0) lim = 0;
    int cc[8]; float vv[8];
    #pragma unroll
    for (int k = 0; k < 8; ++k) {
        int ek = start + k;
        int ec = (ek < end) ? ek : lim;
        cc[k] = cols[ec];
        vv[k] = vals[ec];
    }
    for (int e = start; e < end; e += 8) {
        int c[8]; float v[8];
        #pragma unroll
        for (int k = 0; k < 8; ++k) {
            c[k] = cc[k];
            v[k] = (e + k < end) ? vv[k] : 0.0f;
        }
        #pragma unroll
        for (int k = 0; k < 8; ++k) {
            int ek = e + 8 + k;
            int ec = (ek < end) ? ek : lim;
            cc[k] = cols[ec];
            vv[k] = vals[ec];
        }
        us4 r[8];
        #pragma unroll
        for (int k = 0; k < 8; ++k) r[k] = y4[(size_t)c[k] * 8 + l];
        #pragma unroll
        for (int k = 0; k < 8; ++k) {
            float* a = (k & 1) ? a1 : a0;
            #pragma unroll
            for (int i = 0; i < 4; ++i)
                a[i] = fmaf(bf2f(r[k][i]), v[k], a[i]);
        }
    }
    if (n < N) {
        const f4* __restrict__ b4 = (const f4*)bias;
        f4 bb = b4[l];
        f4 o;
        o.x = fmaxf(a0[0] + a1[0] + bb.x, 0.f);
        o.y = fmaxf(a0[1] + a1[1] + bb.y, 0.f);
        o.z = fmaxf(a0[2] + a1[2] + bb.z, 0.f);
        o.w = fmaxf(a0[3] + a1[3] + bb.w, 0.f);
        f4* op = (f4*)(out + (size_t)n * F + l * 4);
        __builtin_nontemporal_store(o, op);
    }
}

// ---- Fallback (ws too small): proven fp32 kernel ----
__global__ __launch_bounds__(256) void gnn_fp32_kernel(
    const float* __restrict__ x,
    const int*   __restrict__ rows,
    const int*   __restrict__ cols,
    const float* __restrict__ vals,
    const float* __restrict__ W,
    const float* __restrict__ bias,
    float*       __restrict__ out,
    int N, int E) {
    __shared__ float Wt[F * F];
    __shared__ float bS[F];
    int t = threadIdx.x;
    for (int i = t; i < F * F; i += 256)
        Wt[(i & 31) * F + (i >> 5)] = W[i];
    if (t < F) bS[t] = bias[t];
    __syncthreads();
    int lane = t & 63;
    int n = blockIdx.x * 4 + (t >> 6);
    if (n >= N) return;
    int g = lane >> 3, l = lane & 7;
    int target = n + (lane >> 5);
    int lo = 0, hi = E;
    while (lo < hi) { int mid = (lo + hi) >> 1; if (rows[mid] < target) lo = mid + 1; else hi = mid; }
    int start = __shfl(lo, 0), end = __shfl(lo, 32);
    const float4* __restrict__ x4 = (const float4*)x;
    float4 acc0 = {0,0,0,0}, acc1 = {0,0,0,0};
    for (int e0 = start; e0 < end; e0 += 16) {
        int ea = e0 + g, eb = ea + 8;
        if (ea < end) { int c = cols[ea]; float v = vals[ea]; float4 xr = x4[c * 8 + l];
            acc0.x = fmaf(xr.x, v, acc0.x); acc0.y = fmaf(xr.y, v, acc0.y);
            acc0.z = fmaf(xr.z, v, acc0.z); acc0.w = fmaf(xr.w, v, acc0.w); }
        if (eb < end) { int c = cols[eb]; float v = vals[eb]; float4 xr = x4[c * 8 + l];
            acc1.x = fmaf(xr.x, v, acc1.x); acc1.y = fmaf(xr.y, v, acc1.y);
            acc1.z = fmaf(xr.z, v, acc1.z); acc1.w = fmaf(xr.w, v, acc1.w); }
    }
    acc0.x += acc1.x; acc0.y += acc1.y; acc0.z += acc1.z; acc0.w += acc1.w;
    #pragma unroll
    for (int m = 8; m < 64; m <<= 1) {
        acc0.x += __shfl_xor(acc0.x, m); acc0.y += __shfl_xor(acc0.y, m);
        acc0.z += __shfl_xor(acc0.z, m); acc0.w += __shfl_xor(acc0.w, m);
    }
    float comp[4] = {acc0.x, acc0.y, acc0.z, acc0.w};
    int fo = lane & 31;
    float o = bS[fo];
    #pragma unroll
    for (int fi = 0; fi < F; ++fi)
        o = fmaf(__shfl(comp[fi & 3], fi >> 2), Wt[fi * F + fo], o);
    if (lane < F) out[n * F + fo] = fmaxf(o, 0.0f);
}

extern "C" void kernel_launch(void* const* d_in, const int* in_sizes, int n_in,
                              void* d_out, int out_size, void* d_ws, size_t ws_size,
                              hipStream_t stream) {
    const float* x    = (const float*)d_in[0];
    const int*   rows = (const int*)  d_in[1];
    const int*   cols = (const int*)  d_in[2];
    const float* vals = (const float*)d_in[3];
    const float* W    = (const float*)d_in[4];
    const float* bias = (const float*)d_in[5];
    float*       out  = (float*)d_out;

    int N = in_sizes[0] / F;
    int E = in_sizes[1];

    size_t rp_bytes = (size_t)(N + 1) * sizeof(int);
    size_t y_off    = (rp_bytes + 255) & ~(size_t)255;
    size_t need     = y_off + (size_t)N * F * sizeof(unsigned short);

    if (ws_size >= need) {
        int* row_ptr = (int*)d_ws;
        unsigned short* y = (unsigned short*)((char*)d_ws + y_off);
        int nxw  = (N + 63) / 64;
        int ncsr = (E + 1 + 255) / 256;
        prologue_kernel<<<nxw + ncsr, 256, 0, stream>>>(x, W, rows, y, row_ptr, N, E, nxw);

        // occupancy-sized all-resident cooperative grid (cached)
        static int coop_grid = -2;   // -2 = not queried
        if (coop_grid == -2) {
            int perCU = 0, nCU = 0, dev = 0;
            if (hipGetDevice(&dev) == hipSuccess &&
                hipOccupancyMaxActiveBlocksPerMultiprocessor(
                    &perCU, gnn_coop_kernel, 256, 0) == hipSuccess &&
                hipDeviceGetAttribute(&nCU,
                    hipDeviceAttributeMultiprocessorCount, dev) == hipSuccess &&
                perCU > 0 && nCU > 0)
                coop_grid = perCU * nCU;
            else
                coop_grid = -1;      // query failed -> plain path
        }

        bool launched = false;
        if (coop_grid > 0) {
            int nblk_needed = (N + 31) / 32;
            int G = coop_grid < nblk_needed ? coop_grid : nblk_needed;
            int T = (N + G * 32 - 1) / (G * 32);
            int H = (N + 1) / 2;
            void* args[] = {(void*)&y, (void*)&cols, (void*)&vals,
                            (void*)&row_ptr, (void*)&bias, (void*)&out,
                            (void*)&N, (void*)&H, (void*)&T};
            hipError_t err = hipLaunchCooperativeKernel(
                (const void*)gnn_coop_kernel, dim3(G), dim3(256), args, 0, stream);
            launched = (err == hipSuccess);
        }
        if (!launched) {
            gnn_kernel<<<(N + 31) / 32, 256, 0, stream>>>(
                y, cols, vals, row_ptr, bias, out, N);
        }
    } else {
        gnn_fp32_kernel<<<(N + 3) / 4, 256, 0, stream>>>(
            x, rows, cols, vals, W, bias, out, N, E);
    }
}

// Round 7
// 111.624 us; speedup vs baseline: 7.8992x; 7.8992x over previous
//
#include <hip/hip_runtime.h>

#define F 32  // F_IN == F_OUT == 32

typedef __attribute__((ext_vector_type(8))) unsigned short us8;
typedef __attribute__((ext_vector_type(4))) unsigned short us4;
typedef __attribute__((ext_vector_type(4))) float f4;
typedef __attribute__((ext_vector_type(8))) __bf16 bf8;

// ---- bf16 helpers (manual RNE) ----
static __device__ __forceinline__ unsigned short f2bf(float f) {
    unsigned int u = __float_as_uint(f);
    u += 0x7FFF + ((u >> 16) & 1);
    return (unsigned short)(u >> 16);
}
static __device__ __forceinline__ float bf2f(unsigned short s) {
    return __uint_as_float(((unsigned int)s) << 16);
}

// Fused prologue. Blocks [0, nxw): y = x @ W^T via MFMA, 64 nodes/block
// (16-node tile per wave, no LDS). hi/lo bf16 split of x and W keeps
// precision at the fp32-FMA level (store-rounding dominates).
// Blocks [nxw, ...): CSR row-ptr boundary scatter from sorted rows.
__global__ __launch_bounds__(256) void prologue_kernel(
    const float* __restrict__ x, const float* __restrict__ W,
    const int* __restrict__ rows,
    unsigned short* __restrict__ y, int* __restrict__ ptr,
    int N, int E, int nxw) {
    int b = blockIdx.x;
    int t = threadIdx.x;
    if (b < nxw) {
        int lane = t & 63;
        int n0 = (b * 4 + (t >> 6)) * 16;     // 16-node tile per wave
        if (n0 >= N) return;
        int m  = lane & 15;
        int kb = lane >> 4;                    // 0..3 -> k-block of 8
        int k0 = kb * 8;

        // A fragment: x[n0+m][k0..k0+7] (row clamp for generality)
        int ra = n0 + m; if (ra > N - 1) ra = N - 1;
        const f4* __restrict__ xr = (const f4*)(x + (size_t)ra * F + k0);
        f4 xa = xr[0], xb = xr[1];
        float fx[8] = {xa.x, xa.y, xa.z, xa.w, xb.x, xb.y, xb.z, xb.w};
        bf8 Ah, Al;
        #pragma unroll
        for (int i = 0; i < 8; ++i) {
            __bf16 h = (__bf16)fx[i];
            Ah[i] = h;
            Al[i] = (__bf16)(fx[i] - (float)h);
        }

        // B fragments: B[k][n] = W[n][k]; lane holds col n=m (and n=m+16)
        const f4* __restrict__ w0 = (const f4*)(W + (size_t)m * F + k0);
        const f4* __restrict__ w1 = (const f4*)(W + (size_t)(m + 16) * F + k0);
        f4 wa = w0[0], wb = w0[1], wc = w1[0], wd = w1[1];
        float fw0[8] = {wa.x, wa.y, wa.z, wa.w, wb.x, wb.y, wb.z, wb.w};
        float fw1[8] = {wc.x, wc.y, wc.z, wc.w, wd.x, wd.y, wd.z, wd.w};
        bf8 B0h, B0l, B1h, B1l;
        #pragma unroll
        for (int i = 0; i < 8; ++i) {
            __bf16 h0 = (__bf16)fw0[i];
            B0h[i] = h0;
            B0l[i] = (__bf16)(fw0[i] - (float)h0);
            __bf16 h1 = (__bf16)fw1[i];
            B1h[i] = h1;
            B1l[i] = (__bf16)(fw1[i] - (float)h1);
        }

        f4 acc0 = {0.f, 0.f, 0.f, 0.f}, acc1 = {0.f, 0.f, 0.f, 0.f};
        acc0 = __builtin_amdgcn_mfma_f32_16x16x32_bf16(Ah, B0h, acc0, 0, 0, 0);
        acc0 = __builtin_amdgcn_mfma_f32_16x16x32_bf16(Ah, B0l, acc0, 0, 0, 0);
        acc0 = __builtin_amdgcn_mfma_f32_16x16x32_bf16(Al, B0h, acc0, 0, 0, 0);
        acc1 = __builtin_amdgcn_mfma_f32_16x16x32_bf16(Ah, B1h, acc1, 0, 0, 0);
        acc1 = __builtin_amdgcn_mfma_f32_16x16x32_bf16(Ah, B1l, acc1, 0, 0, 0);
        acc1 = __builtin_amdgcn_mfma_f32_16x16x32_bf16(Al, B1h, acc1, 0, 0, 0);

        // C/D layout (verified m89): col = lane&15, row = (lane>>4)*4 + r
        int mr = n0 + kb * 4;
        #pragma unroll
        for (int r = 0; r < 4; ++r) {
            int row = mr + r;
            if (row < N) {
                y[(size_t)row * F + m]      = f2bf(acc0[r]);
                y[(size_t)row * F + m + 16] = f2bf(acc1[r]);
            }
        }
    } else {
        int e = (b - nxw) * 256 + t;
        if (e > E) return;
        int prev = (e == 0) ? -1 : rows[e - 1];
        int cur  = (e == E) ? N  : rows[e];
        for (int r = prev + 1; r <= cur; ++r) ptr[r] = e;
    }
}

// Hot kernel: wave = 8 nodes x 8 lanes. Lane l of group g loads us4
// (8B = features 4l..4l+3 of a 64B bf16 row; 8 lanes = one 64B line).
// 8-edge unroll with clamped predication; index loads software-pipelined
// one chunk ahead so cols/vals latency overlaps gathers+FMA. 2 acc chains.
// Best-measured config (R1: 111.8 us total). VGPR < 64 -> 8 waves/SIMD.
__global__ __launch_bounds__(256) void gnn_kernel(
    const unsigned short* __restrict__ y,
    const int*   __restrict__ cols,
    const float* __restrict__ vals,
    const int*   __restrict__ row_ptr,
    const float* __restrict__ bias,
    float*       __restrict__ out, int N) {
    int t = threadIdx.x;
    int lane = t & 63;
    int g = lane >> 3;           // node group 0..7
    int l = lane & 7;            // feature slice: 4l..4l+3
    int n = (blockIdx.x * 4 + (t >> 6)) * 8 + g;
    int start = 0, end = 0;
    if (n < N) { start = row_ptr[n]; end = row_ptr[n + 1]; }

    const us4* __restrict__ y4 = (const us4*)y;   // 8 x us4 per row

    float a0[4], a1[4];
    #pragma unroll
    for (int i = 0; i < 4; ++i) { a0[i] = 0.f; a1[i] = 0.f; }

    int lim = end - 1; if (lim < 0) lim = 0;

    // prefetch first index chunk
    int cc[8]; float vv[8];
    #pragma unroll
    for (int k = 0; k < 8; ++k) {
        int ek = start + k;
        int ec = (ek < end) ? ek : lim;
        cc[k] = cols[ec];
        vv[k] = vals[ec];
    }

    for (int e = start; e < end; e += 8) {
        int c[8]; float v[8];
        #pragma unroll
        for (int k = 0; k < 8; ++k) {
            c[k] = cc[k];
            v[k] = (e + k < end) ? vv[k] : 0.0f;   // predicate via value
        }
        // pipeline: issue next chunk's index loads before the gathers
        #pragma unroll
        for (int k = 0; k < 8; ++k) {
            int ek = e + 8 + k;
            int ec = (ek < end) ? ek : lim;
            cc[k] = cols[ec];
            vv[k] = vals[ec];
        }
        us4 r[8];
        #pragma unroll
        for (int k = 0; k < 8; ++k) r[k] = y4[(size_t)c[k] * 8 + l];
        #pragma unroll
        for (int k = 0; k < 8; ++k) {
            float* a = (k & 1) ? a1 : a0;          // 2 chains
            #pragma unroll
            for (int i = 0; i < 4; ++i)
                a[i] = fmaf(bf2f(r[k][i]), v[k], a[i]);
        }
    }

    if (n < N) {
        const f4* __restrict__ b4 = (const f4*)bias;
        f4 bb = b4[l];
        f4 o;
        o.x = fmaxf(a0[0] + a1[0] + bb.x, 0.f);
        o.y = fmaxf(a0[1] + a1[1] + bb.y, 0.f);
        o.z = fmaxf(a0[2] + a1[2] + bb.z, 0.f);
        o.w = fmaxf(a0[3] + a1[3] + bb.w, 0.f);
        f4* op = (f4*)(out + (size_t)n * F + l * 4);
        __builtin_nontemporal_store(o, op);
    }
}

// ---- Fallback (ws too small): proven fp32 kernel ----
__global__ __launch_bounds__(256) void gnn_fp32_kernel(
    const float* __restrict__ x,
    const int*   __restrict__ rows,
    const int*   __restrict__ cols,
    const float* __restrict__ vals,
    const float* __restrict__ W,
    const float* __restrict__ bias,
    float*       __restrict__ out,
    int N, int E) {
    __shared__ float Wt[F * F];
    __shared__ float bS[F];
    int t = threadIdx.x;
    for (int i = t; i < F * F; i += 256)
        Wt[(i & 31) * F + (i >> 5)] = W[i];
    if (t < F) bS[t] = bias[t];
    __syncthreads();
    int lane = t & 63;
    int n = blockIdx.x * 4 + (t >> 6);
    if (n >= N) return;
    int g = lane >> 3, l = lane & 7;
    int target = n + (lane >> 5);
    int lo = 0, hi = E;
    while (lo < hi) { int mid = (lo + hi) >> 1; if (rows[mid] < target) lo = mid + 1; else hi = mid; }
    int start = __shfl(lo, 0), end = __shfl(lo, 32);
    const float4* __restrict__ x4 = (const float4*)x;
    float4 acc0 = {0,0,0,0}, acc1 = {0,0,0,0};
    for (int e0 = start; e0 < end; e0 += 16) {
        int ea = e0 + g, eb = ea + 8;
        if (ea < end) { int c = cols[ea]; float v = vals[ea]; float4 xr = x4[c * 8 + l];
            acc0.x = fmaf(xr.x, v, acc0.x); acc0.y = fmaf(xr.y, v, acc0.y);
            acc0.z = fmaf(xr.z, v, acc0.z); acc0.w = fmaf(xr.w, v, acc0.w); }
        if (eb < end) { int c = cols[eb]; float v = vals[eb]; float4 xr = x4[c * 8 + l];
            acc1.x = fmaf(xr.x, v, acc1.x); acc1.y = fmaf(xr.y, v, acc1.y);
            acc1.z = fmaf(xr.z, v, acc1.z); acc1.w = fmaf(xr.w, v, acc1.w); }
    }
    acc0.x += acc1.x; acc0.y += acc1.y; acc0.z += acc1.z; acc0.w += acc1.w;
    #pragma unroll
    for (int m = 8; m < 64; m <<= 1) {
        acc0.x += __shfl_xor(acc0.x, m); acc0.y += __shfl_xor(acc0.y, m);
        acc0.z += __shfl_xor(acc0.z, m); acc0.w += __shfl_xor(acc0.w, m);
    }
    float comp[4] = {acc0.x, acc0.y, acc0.z, acc0.w};
    int fo = lane & 31;
    float o = bS[fo];
    #pragma unroll
    for (int fi = 0; fi < F; ++fi)
        o = fmaf(__shfl(comp[fi & 3], fi >> 2), Wt[fi * F + fo], o);
    if (lane < F) out[n * F + fo] = fmaxf(o, 0.0f);
}

extern "C" void kernel_launch(void* const* d_in, const int* in_sizes, int n_in,
                              void* d_out, int out_size, void* d_ws, size_t ws_size,
                              hipStream_t stream) {
    const float* x    = (const float*)d_in[0];
    const int*   rows = (const int*)  d_in[1];
    const int*   cols = (const int*)  d_in[2];
    const float* vals = (const float*)d_in[3];
    const float* W    = (const float*)d_in[4];
    const float* bias = (const float*)d_in[5];
    float*       out  = (float*)d_out;

    int N = in_sizes[0] / F;
    int E = in_sizes[1];

    size_t rp_bytes = (size_t)(N + 1) * sizeof(int);
    size_t y_off    = (rp_bytes + 255) & ~(size_t)255;
    size_t need     = y_off + (size_t)N * F * sizeof(unsigned short);

    if (ws_size >= need) {
        int* row_ptr = (int*)d_ws;
        unsigned short* y = (unsigned short*)((char*)d_ws + y_off);
        int nxw  = (N + 63) / 64;
        int ncsr = (E + 1 + 255) / 256;
        prologue_kernel<<<nxw + ncsr, 256, 0, stream>>>(x, W, rows, y, row_ptr, N, E, nxw);
        gnn_kernel<<<(N + 31) / 32, 256, 0, stream>>>(y, cols, vals, row_ptr, bias, out, N);
    } else {
        gnn_fp32_kernel<<<(N + 3) / 4, 256, 0, stream>>>(
            x, rows, cols, vals, W, bias, out, N, E);
    }
}